// Round 13
// baseline (762.196 us; speedup 1.0000x reference)
//
#include <hip/hip_runtime.h>
#include <hip/hip_bf16.h>

typedef __attribute__((ext_vector_type(4))) float f32x4;
typedef __attribute__((ext_vector_type(8))) short short8;

#define DEVI __device__ __forceinline__

DEVI unsigned short f2bf(float x) {
  union { float f; unsigned u; } v; v.f = x;
  unsigned r = v.u + 0x7fffu + ((v.u >> 16) & 1u);
  return (unsigned short)(r >> 16);
}
DEVI float bf2f(unsigned short h) {
  union { unsigned u; float f; } v; v.u = ((unsigned)h) << 16;
  return v.f;
}

DEVI void gld16(const void* g, void* l) {
  __builtin_amdgcn_global_load_lds(
      (const __attribute__((address_space(1))) void*)g,
      (__attribute__((address_space(3))) void*)l, 16, 0, 0);
}

#define MFMA __builtin_amdgcn_mfma_f32_16x16x32_bf16

// ---------- zero flags ----------
__global__ __launch_bounds__(128) void zero_flags(unsigned* __restrict__ f) {
  f[threadIdx.x] = 0;
}

// ---------- prep ----------
// whh0/whh1/wih1 -> bf16 MFMA-fragment order (kt-major, r8 layout):
//   element e: slot=e>>3, r=e&7; lane=slot&63, ni=(slot>>6)&3, wd=(slot>>8)&7,
//   kt=slot>>11; col=wd*64+ni*16+(lane&15); kr=kt*32+(lane>>4)*8+r.
// wih0 -> plain bf16; embed -> plain bf16.
__global__ __launch_bounds__(256) void prep_cvt(
    const float* __restrict__ whh0, const float* __restrict__ whh1,
    const float* __restrict__ wih1, const float* __restrict__ wih0,
    const float* __restrict__ embed,
    short* __restrict__ o_whh0fr, short* __restrict__ o_whh1fr,
    short* __restrict__ o_wih1fr, short* __restrict__ o_wih0,
    short* __restrict__ o_emb) {
  int i = blockIdx.x * 256 + threadIdx.x;
  if (i < 786432) {
    const float* src = (i < 262144) ? whh0 : (i < 524288) ? whh1 : wih1;
    short* dst = (i < 262144) ? o_whh0fr : (i < 524288) ? o_whh1fr : o_wih1fr;
    int e = i & 262143;
    int slot = e >> 3, r = e & 7;
    int lane = slot & 63, ni = (slot >> 6) & 3, wd = (slot >> 8) & 7, kt = slot >> 11;
    int col = wd * 64 + ni * 16 + (lane & 15);
    int kr = kt * 32 + (lane >> 4) * 8 + r;
    dst[e] = (short)f2bf(src[col * 512 + kr]);
    return;
  }
  if (i < 917504) { int j = i - 786432; o_wih0[j] = (short)f2bf(wih0[j]); return; }
  {
    int j = i - 917504;
    if (j < 8192000) o_emb[j] = (short)f2bf(embed[j]);
  }
}

// ---------- GEMM0: pre0 = emb @ W_ih0^T + bih0 + bhh0 (bf16 out) ----------
template<int KDIM, bool GATHER>
__global__ __launch_bounds__(256) void gemm_pre(
    const short* __restrict__ embbf, const int* __restrict__ xtok,
    const short* __restrict__ Abf, const short* __restrict__ Bbf,
    const float* __restrict__ bias_a, const float* __restrict__ bias_b,
    short* __restrict__ out) {
  __shared__ __align__(16) char smem[65536];
  const int tid = threadIdx.x;
  const int bM = (int)blockIdx.x >> 2;
  const int bN = (int)blockIdx.x & 3;
  const int m0 = bM * 128, n0 = bN * 128;
  const int lane = tid & 63, wid = tid >> 6;
  const int wm = wid >> 1, wn = wid & 1;
  const int l15 = lane & 15, lk = lane >> 4;

  const char* aSrc[4];
  const char* bSrc[4];
#pragma unroll
  for (int i = 0; i < 4; ++i) {
    int rloc = wid * 32 + i * 8 + (lane >> 3);
    int chunk = (((lane & 7) ^ (rloc & 7)) << 4);
    if (GATHER) {
      int r = m0 + rloc;
      int t = r >> 11, n = r & 2047;
      int tok = xtok[(n << 5) + t];
      aSrc[i] = (const char*)(embbf + (size_t)tok * 256) + chunk;
    } else {
      aSrc[i] = (const char*)(Abf + (size_t)(m0 + rloc) * KDIM) + chunk;
    }
    bSrc[i] = (const char*)(Bbf + (size_t)(n0 + rloc) * KDIM) + chunk;
  }

  f32x4 acc[4][4];
#pragma unroll
  for (int i = 0; i < 4; ++i)
#pragma unroll
    for (int j = 0; j < 4; ++j) acc[i][j] = (f32x4){0.f, 0.f, 0.f, 0.f};

#define STAGE(BUF, KB)                                        \
  do {                                                        \
    char* ab = smem + (BUF)*32768 + wid * 4096;               \
    char* bb = smem + (BUF)*32768 + 16384 + wid * 4096;       \
    _Pragma("unroll") for (int i = 0; i < 4; ++i) {           \
      gld16(aSrc[i] + (size_t)(KB)*2, ab + i * 1024);         \
      gld16(bSrc[i] + (size_t)(KB)*2, bb + i * 1024);         \
    }                                                         \
  } while (0)

  STAGE(0, 0);
  int cur = 0;
  for (int kb = 0; kb < KDIM; kb += 64) {
    __syncthreads();
    if (kb + 64 < KDIM) STAGE(cur ^ 1, kb + 64);
    const char* As = smem + cur * 32768;
    const char* Bs = As + 16384;
#pragma unroll
    for (int kt = 0; kt < 2; ++kt) {
      short8 av[4], bv[4];
#pragma unroll
      for (int mi = 0; mi < 4; ++mi) {
        int row = wm * 64 + mi * 16 + l15;
        int off = (row * 128 + kt * 64 + lk * 16) ^ ((row & 7) << 4);
        av[mi] = *(const short8*)(As + off);
      }
#pragma unroll
      for (int ni = 0; ni < 4; ++ni) {
        int col = wn * 64 + ni * 16 + l15;
        int off = (col * 128 + kt * 64 + lk * 16) ^ ((col & 7) << 4);
        bv[ni] = *(const short8*)(Bs + off);
      }
#pragma unroll
      for (int mi = 0; mi < 4; ++mi)
#pragma unroll
        for (int ni = 0; ni < 4; ++ni)
          acc[mi][ni] = MFMA(av[mi], bv[ni], acc[mi][ni], 0, 0, 0);
    }
    cur ^= 1;
  }
#undef STAGE

  __syncthreads();
  float bsum[4];
#pragma unroll
  for (int ni = 0; ni < 4; ++ni) {
    int cg = n0 + wn * 64 + ni * 16 + l15;
    bsum[ni] = bias_a[cg] + bias_b[cg];
  }
  short* Cs = (short*)smem;
#pragma unroll
  for (int mi = 0; mi < 4; ++mi)
#pragma unroll
    for (int ni = 0; ni < 4; ++ni)
#pragma unroll
      for (int r = 0; r < 4; ++r) {
        int row = wm * 64 + mi * 16 + lk * 4 + r;
        int col = wn * 64 + ni * 16 + l15;
        Cs[row * 128 + col] = (short)f2bf(acc[mi][ni][r] + bsum[ni]);
      }
  __syncthreads();
  {
    int row = tid >> 1, colh = (tid & 1) * 64;
    size_t gbase = (size_t)(m0 + row) * 512 + n0 + colh;
#pragma unroll
    for (int c = 0; c < 8; ++c)
      *(short8*)(out + gbase + c * 8) = *(const short8*)&Cs[row * 128 + colh + c * 8];
  }
}

// ---------- shared stream core (M=32, kt0 stationary + 2-slot ring kt1..15) ----------
DEVI void stream_core(const char* ab0, const char* ab1, const char* wstw,
                      char* ringw, const short* wsl, int lane, int lk16, int axor,
                      f32x4 (&acc)[2][4]) {
  {  // kt0 from Wst (always resident; landed before first use)
    short8 a0 = *(const short8*)(ab0 + (lk16 ^ axor));
    short8 a1 = *(const short8*)(ab1 + (lk16 ^ axor));
#pragma unroll
    for (int ni = 0; ni < 4; ++ni) {
      short8 b = *(const short8*)(wstw + ni * 1024 + lane * 16);
      acc[0][ni] = MFMA(a0, b, acc[0][ni], 0, 0, 0);
      acc[1][ni] = MFMA(a1, b, acc[1][ni], 0, 0, 0);
    }
  }
#pragma unroll
  for (int j = 0; j < 15; ++j) {
    const int kt = 1 + j;
    char* slot = ringw + (j & 1) * 4096;
    if (j >= 2) {
      asm volatile("s_waitcnt vmcnt(4)" ::: "memory");
      __builtin_amdgcn_sched_barrier(0);
    }
    short8 a0 = *(const short8*)(ab0 + ((kt * 64 + lk16) ^ axor));
    short8 a1 = *(const short8*)(ab1 + ((kt * 64 + lk16) ^ axor));
    short8 b0 = *(const short8*)(slot + lane * 16);
    short8 b1 = *(const short8*)(slot + 1024 + lane * 16);
    short8 b2 = *(const short8*)(slot + 2048 + lane * 16);
    short8 b3 = *(const short8*)(slot + 3072 + lane * 16);
    acc[0][0] = MFMA(a0, b0, acc[0][0], 0, 0, 0);
    acc[1][0] = MFMA(a1, b0, acc[1][0], 0, 0, 0);
    acc[0][1] = MFMA(a0, b1, acc[0][1], 0, 0, 0);
    acc[1][1] = MFMA(a1, b1, acc[1][1], 0, 0, 0);
    acc[0][2] = MFMA(a0, b2, acc[0][2], 0, 0, 0);
    acc[1][2] = MFMA(a1, b2, acc[1][2], 0, 0, 0);
    acc[0][3] = MFMA(a0, b3, acc[0][3], 0, 0, 0);
    acc[1][3] = MFMA(a1, b3, acc[1][3], 0, 0, 0);
    // step-invariant slot refill: S0 holds odd kts, S1 even.
    const int ktr = (j <= 12) ? (kt + 2) : (j == 13 ? 2 : 1);
    const short* rs = wsl + ktr * 16384;
#pragma unroll
    for (int ni = 0; ni < 4; ++ni) gld16(rs + ni * 512, slot + ni * 1024);
  }
}

// ---------- fused pipeline: role P(recur0) -> G(gemm pre1) -> C(recur1) ----------
// 192 blocks = 64 groups x 3 roles; each block: 32 seqs, 8 waves, LDS 160 KB,
// 1 block/CU. Mailboxes: h0mail aliases pre0 (per-t slots); p1mail separate.
// Flags: flagP[64] @0, flagG[64] @64 (agent-scope atomics; r7-proven).
__global__ __launch_bounds__(512) void pipeline(
    const short* __restrict__ pre0,  // [32][2048][512] bf16 (gemm0 out)
    unsigned* h0mail,                // u32 view of pre0 (aliased mailbox)
    unsigned* p1mail,                // [32][2048][512] bf16 as u32
    const short* __restrict__ whh0fr, const short* __restrict__ wih1fr,
    const short* __restrict__ whh1fr,
    const float* __restrict__ bih1, const float* __restrict__ bhh1,
    float* __restrict__ h1out,       // [2048][512] f32
    unsigned* flags) {
  __shared__ __align__(16) char lds[163840];
  char* Wst   = lds;             // 32 KB: [wid][ni][lane*16B] (kt0)
  char* ring  = lds + 32768;     // 64 KB: [wid][slot2][ni][lane*16B]
  char* atile = lds + 98304;     // 32 KB: A tile (h or h0), 32 rows x 1 KB, swizzled
  char* ptile = lds + 131072;    // 32 KB: pre tile, linear (P, C)
  const int tid = threadIdx.x;
  const int lane = tid & 63, wid = tid >> 6;
  const int l15 = lane & 15, lk = lane >> 4;
  const int role = (int)blockIdx.x >> 6;  // 0=P, 1=G, 2=C
  const int g = (int)blockIdx.x & 63;
  const int seq0 = g * 32;

  const short* wfr = (role == 0) ? whh0fr : (role == 1) ? wih1fr : whh1fr;
  const short* wsl = wfr + wid * 2048 + lane * 8;
  char* wstw = Wst + wid * 4096;
  char* ringw = ring + wid * 8192;

  // prologue: Wst<-kt0, S0<-kt1, S1<-kt2
#pragma unroll
  for (int ni = 0; ni < 4; ++ni) gld16(wsl + ni * 512, wstw + ni * 1024);
#pragma unroll
  for (int ni = 0; ni < 4; ++ni) gld16(wsl + 16384 + ni * 512, ringw + ni * 1024);
#pragma unroll
  for (int ni = 0; ni < 4; ++ni) gld16(wsl + 32768 + ni * 512, ringw + 4096 + ni * 1024);

  float bsum[4];
  if (role == 1) {
#pragma unroll
    for (int ni = 0; ni < 4; ++ni) {
      int c = wid * 64 + ni * 16 + l15;
      bsum[ni] = bih1[c] + bhh1[c];
    }
  } else {  // zero h(-1) tile (32 KB)
    short8 z = {0, 0, 0, 0, 0, 0, 0, 0};
#pragma unroll
    for (int q = 0; q < 4; ++q) *(short8*)(atile + tid * 64 + q * 16) = z;
  }
  __syncthreads();  // drains prologue vmcnt -> Wst/S0/S1 resident

  const int axor = (l15 & 7) << 4;
  const int lk16 = lk * 16;
  const char* ab0 = atile + l15 * 1024;
  const char* ab1 = atile + (16 + l15) * 1024;

#pragma unroll 1
  for (int t = 0; t < 32; ++t) {
    f32x4 acc[2][4];
#pragma unroll
    for (int m = 0; m < 2; ++m)
#pragma unroll
      for (int ni = 0; ni < 4; ++ni) acc[m][ni] = (f32x4){0.f, 0.f, 0.f, 0.f};

    if (role == 0) {
      // stage pre0 tile (own group's rows; consumed after B1, then overwritten as mailbox)
      const short* ps = pre0 + ((size_t)t * 2048 + seq0 + wid * 4) * 512 + lane * 8;
#pragma unroll
      for (int i = 0; i < 4; ++i) gld16(ps + (size_t)i * 512, ptile + (wid * 4 + i) * 1024);
    } else {
      // poll upstream flag, then pull mailbox tile (agent-scope atomic loads)
      const unsigned* fl = flags + (role == 1 ? g : 64 + g);
      if (tid == 0) {
        int guard = 0;
        while (__hip_atomic_load(fl, __ATOMIC_RELAXED, __HIP_MEMORY_SCOPE_AGENT) <
               (unsigned)(t + 1)) {
          if (++guard > (1 << 17)) break;
        }
      }
      __syncthreads();  // B0a: data globally visible; prev step's A-reads done
      const unsigned* src =
          (role == 1 ? h0mail : p1mail) + ((size_t)t * 2048 + seq0) * 256;
      unsigned v[16];
#pragma unroll
      for (int i = 0; i < 16; ++i) {
        int u = i * 512 + tid;
        v[i] = __hip_atomic_load(src + (u >> 8) * 256 + (u & 255),
                                 __ATOMIC_RELAXED, __HIP_MEMORY_SCOPE_AGENT);
      }
      if (role == 1) {
#pragma unroll
        for (int i = 0; i < 16; ++i) {
          int u = i * 512 + tid, row = u >> 8, cp = u & 255;
          *(unsigned*)(atile + row * 1024 + ((cp * 4) ^ ((row & 7) << 4))) = v[i];
        }
        __syncthreads();  // B0b: A-tile ready
      } else {
#pragma unroll
        for (int i = 0; i < 16; ++i) {
          int u = i * 512 + tid, row = u >> 8, cp = u & 255;
          *(unsigned*)(ptile + row * 1024 + cp * 4) = v[i];
        }
      }
    }

    stream_core(ab0, ab1, wstw, ringw, wsl, lane, lk16, axor, acc);

    if (role == 1) {
      // publish pre1[t] = acc + bias (bf16, u32-packed, agent atomics)
      unsigned* dst = p1mail + ((size_t)t * 2048 + seq0) * 256;
#pragma unroll
      for (int m = 0; m < 2; ++m)
#pragma unroll
        for (int ni = 0; ni < 4; ++ni)
#pragma unroll
          for (int r = 0; r < 4; ++r) {
            int row = m * 16 + lk * 4 + r;
            unsigned short hv = f2bf(acc[m][ni][r] + bsum[ni]);
            int ov = __shfl_xor((int)hv, 1);
            if ((lane & 1) == 0)
              __hip_atomic_store(dst + row * 256 + wid * 32 + ni * 8 + (l15 >> 1),
                                 (unsigned)hv | ((unsigned)ov << 16),
                                 __ATOMIC_RELAXED, __HIP_MEMORY_SCOPE_AGENT);
          }
      asm volatile("s_waitcnt vmcnt(0)" ::: "memory");
      __syncthreads();  // B2: all waves' publishes drained
      if (tid == 0)
        __hip_atomic_store(flags + 64 + g, (unsigned)(t + 1),
                           __ATOMIC_RELAXED, __HIP_MEMORY_SCOPE_AGENT);
    } else {
      __syncthreads();  // B1: ptile staged/visible; all A-reads of h(t-1) done
      // epilogue: h(t) = relu(acc + pre) -> A-tile (swizzled); P publishes; C tail-writes
      unsigned* dst = (role == 0) ? h0mail + ((size_t)t * 2048 + seq0) * 256 : nullptr;
#pragma unroll
      for (int m = 0; m < 2; ++m)
#pragma unroll
        for (int ni = 0; ni < 4; ++ni)
#pragma unroll
          for (int r = 0; r < 4; ++r) {
            int row = m * 16 + lk * 4 + r;
            int col = wid * 64 + ni * 16 + l15;
            float pv = bf2f(*(const unsigned short*)(ptile + row * 1024 + col * 2));
            float vv = fmaxf(acc[m][ni][r] + pv, 0.f);
            unsigned short hv = f2bf(vv);
            *(short*)(atile + row * 1024 + ((col * 2) ^ ((row & 7) << 4))) = (short)hv;
            if (role == 0) {
              int ov = __shfl_xor((int)hv, 1);
              if ((lane & 1) == 0)
                __hip_atomic_store(dst + row * 256 + wid * 32 + ni * 8 + (l15 >> 1),
                                   (unsigned)hv | ((unsigned)ov << 16),
                                   __ATOMIC_RELAXED, __HIP_MEMORY_SCOPE_AGENT);
            } else if (t == 31) {
              h1out[(size_t)(seq0 + row) * 512 + col] = vv;
            }
          }
      if (role == 0) {
        asm volatile("s_waitcnt vmcnt(0)" ::: "memory");
        __syncthreads();  // B2: publishes drained block-wide; h(t) visible
        if (tid == 0)
          __hip_atomic_store(flags + g, (unsigned)(t + 1),
                             __ATOMIC_RELAXED, __HIP_MEMORY_SCOPE_AGENT);
      } else {
        __syncthreads();  // B2: h(t) visible
      }
    }
  }
}

// ---------- head: s[b,n] = h_n.(wl-wg) + (sum_n h).wg + b_pred ----------
__global__ __launch_bounds__(512) void predict(
    const float* __restrict__ h1, const float* __restrict__ Wp,
    const float* __restrict__ bp, float* __restrict__ out) {
  const int b = blockIdx.x, tid = threadIdx.x;
  const int lane = tid & 63, wid = tid >> 6;
  __shared__ float red[8];
  __shared__ float sgd_s;
  const float* hb = h1 + (size_t)b * 256 * 512;
  float s = 0.f;
  for (int n = 0; n < 256; ++n) s += hb[(size_t)n * 512 + tid];
  float p = s * Wp[512 + tid];
#pragma unroll
  for (int o = 32; o; o >>= 1) p += __shfl_xor(p, o);
  if (lane == 0) red[wid] = p;
  __syncthreads();
  if (tid == 0) {
    float q = 0.f;
#pragma unroll
    for (int i = 0; i < 8; ++i) q += red[i];
    sgd_s = q;
  }
  __syncthreads();
  const float sgd = sgd_s + bp[0];
  float wd[8];
  const int k0 = lane * 8;
#pragma unroll
  for (int j = 0; j < 8; ++j) wd[j] = Wp[k0 + j] - Wp[512 + k0 + j];
  for (int c = 0; c < 32; ++c) {
    int n = wid * 32 + c;
    const float* hr = hb + (size_t)n * 512 + k0;
    float d = 0.f;
#pragma unroll
    for (int j = 0; j < 8; ++j) d += hr[j] * wd[j];
#pragma unroll
    for (int o = 1; o < 64; o <<= 1) d += __shfl_xor(d, o);
    if (lane == 0) out[b * 256 + n] = d + sgd;
  }
}

extern "C" void kernel_launch(void* const* d_in, const int* in_sizes, int n_in,
                              void* d_out, int out_size, void* d_ws, size_t ws_size,
                              hipStream_t stream) {
  const int* x = (const int*)d_in[0];
  const float* embed = (const float*)d_in[1];
  const float* Wih0 = (const float*)d_in[2];
  const float* Whh0 = (const float*)d_in[3];
  const float* bih0 = (const float*)d_in[4];
  const float* bhh0 = (const float*)d_in[5];
  const float* Wih1 = (const float*)d_in[6];
  const float* Whh1 = (const float*)d_in[7];
  const float* bih1 = (const float*)d_in[8];
  const float* bhh1 = (const float*)d_in[9];
  const float* Wpred = (const float*)d_in[10];
  const float* bpred = (const float*)d_in[11];
  float* out = (float*)d_out;

  char* ws = (char*)d_ws;
  short* whh0_fr = (short*)ws;                          // 512 KB
  short* whh1_fr = (short*)(ws + 524288);               // 512 KB
  short* wih1_fr = (short*)(ws + 1048576);              // 512 KB
  short* wih0_bf = (short*)(ws + 1572864);              // 256 KB
  unsigned* flags = (unsigned*)(ws + 1835008);          // 512 B
  short* pre0    = (short*)(ws + 2097152);              // 64 MB (also h0 mailbox)
  short* p1m     = (short*)(ws + 2097152 + 67108864);   // 64 MB (pre1 mailbox)
  float* h1      = (float*)(ws + 2097152 + 2ll * 67108864);  // 4 MB
  short* emb_bf  = p1m;  // 16 MB alias: live only during prep+gemm0

  zero_flags<<<1, 128, 0, stream>>>(flags);
  prep_cvt<<<35584, 256, 0, stream>>>(Whh0, Whh1, Wih1, Wih0, embed,
                                      whh0_fr, whh1_fr, wih1_fr, wih0_bf, emb_bf);
  gemm_pre<256, true><<<2048, 256, 0, stream>>>(emb_bf, x, nullptr, wih0_bf,
                                                bih0, bhh0, pre0);
  pipeline<<<192, 512, 0, stream>>>(pre0, (unsigned*)pre0, (unsigned*)p1m,
                                    whh0_fr, wih1_fr, whh1_fr, bih1, bhh1,
                                    h1, flags);
  predict<<<8, 512, 0, stream>>>(h1, Wpred, bpred, out);
}